// Round 6
// baseline (325.838 us; speedup 1.0000x reference)
//
#include <hip/hip_runtime.h>
#include <stdint.h>

#define GLOBAL_AS __attribute__((address_space(1)))
#define LDS_AS    __attribute__((address_space(3)))

typedef __attribute__((ext_vector_type(8))) short bf16x8;   // 8 bf16 = 4 VGPRs
typedef __attribute__((ext_vector_type(4))) float f32x4;

#define B_DIM 2048
#define D_DIM 4096
#define Q_DIM 1024
#define EPSF  1e-8f

__device__ __forceinline__ unsigned short f2bf(float f) {
  union { float f; unsigned int u; } v; v.f = f;
  unsigned int u = v.u;
  u += 0x7FFFu + ((u >> 16) & 1u);   // round-to-nearest-even
  return (unsigned short)(u >> 16);
}

// ---------------- K0: f32 -> bf16 conversion (x, W_phi, W_dde) ----------------
// G11 recipe: 2048 blocks, grid-stride. Three branch-free region loops.
#define NX4    2097152u   // 2048*4096/4
#define NWPHI4 4194304u   // 4096*4096/4
#define NWDDE4 1048576u   // 1024*4096/4

__global__ __launch_bounds__(256) void k_convert(
    const float* __restrict__ x, const float* __restrict__ wphi,
    const float* __restrict__ wdde,
    unsigned short* __restrict__ xb, unsigned short* __restrict__ wphib,
    unsigned short* __restrict__ wddeb) {
  const unsigned int nth = gridDim.x * 256u;
  const unsigned int tid = blockIdx.x * 256u + threadIdx.x;
  for (unsigned int i = tid; i < NX4; i += nth) {
    float4 v = ((const float4*)x)[i];
    ((ushort4*)xb)[i] = make_ushort4(f2bf(v.x), f2bf(v.y), f2bf(v.z), f2bf(v.w));
  }
  for (unsigned int i = tid; i < NWPHI4; i += nth) {
    float4 v = ((const float4*)wphi)[i];
    ((ushort4*)wphib)[i] = make_ushort4(f2bf(v.x), f2bf(v.y), f2bf(v.z), f2bf(v.w));
  }
  for (unsigned int i = tid; i < NWDDE4; i += nth) {
    float4 v = ((const float4*)wdde)[i];
    ((ushort4*)wddeb)[i] = make_ushort4(f2bf(v.x), f2bf(v.y), f2bf(v.z), f2bf(v.w));
  }
}

// Swizzle: LDS chunk c (16B) holds global k-chunk (c&7)^((c>>3)&7) of row c>>3.
// Fragment read of k-chunk kc, row r -> LDS chunk r*8 + (kc ^ (r&7)).
// Bank math: row stride 64 el = 32 dwords -> addr mod 32 = (kc^(lm&7))*4 -> 8
// distinct bank-quads over 16 lanes -> 2-way aliasing = free (m136).

// ---------------- K1s: GEMM1 split-K=2, partial stores (CONTROL, 84us/816TF) ----------------
// grid (32,16,2) = 1024 blocks -> 4/CU resident. Resident-block TLP is the lever:
// 512 blocks (2/CU) measured 533 TF, 1024 blocks (4/CU) measured 816 TF.
__global__ __launch_bounds__(256) void k_gemm1s(
    const unsigned short* __restrict__ A, const unsigned short* __restrict__ Bm,
    float* __restrict__ p0, float* __restrict__ p1) {
  __shared__ __align__(16) unsigned short sAB[2 * 128 * 64];  // 32 KB
  const int t = threadIdx.x;
  const int lane = t & 63;
  const int w = t >> 6;
  const int bn = blockIdx.x;   // 0..31
  const int bm = blockIdx.y;   // 0..15
  const int sk = blockIdx.z;   // 0..1
  const int rowA0 = bm * 128;
  const int rowB0 = bn * 128;
  const int kbeg = sk * 2048;

  const unsigned short* gA[4]; const unsigned short* gB[4];
  unsigned short *lA[4], *lB[4];
#pragma unroll
  for (int p = 0; p < 4; ++p) {
    const int c = t + p * 256;
    const int row = c >> 3;
    const int kcg = (c & 7) ^ (row & 7);
    gA[p] = A  + (size_t)(rowA0 + row) * D_DIM + kbeg + kcg * 8;
    gB[p] = Bm + (size_t)(rowB0 + row) * D_DIM + kbeg + kcg * 8;
    lA[p] = &sAB[c * 8];
    lB[p] = &sAB[8192 + c * 8];
  }

  f32x4 acc[4][4] = {};
  const int lm = lane & 15;
  const int lq = lane >> 4;
  const int mbase = (w >> 1) * 64;
  const int nbase = (w & 1) * 64;
  const int rsw = lm & 7;

  for (int k0 = 0; k0 < 2048; k0 += 64) {
#pragma unroll
    for (int p = 0; p < 4; ++p) {
      __builtin_amdgcn_global_load_lds((const GLOBAL_AS unsigned int*)(gA[p] + k0), (LDS_AS unsigned int*)lA[p], 16, 0, 0);
      __builtin_amdgcn_global_load_lds((const GLOBAL_AS unsigned int*)(gB[p] + k0), (LDS_AS unsigned int*)lB[p], 16, 0, 0);
    }
    __syncthreads();
#pragma unroll
    for (int ks = 0; ks < 2; ++ks) {
      const int kc = ks * 4 + lq;
      const int csw = (kc ^ rsw) * 8;
      bf16x8 af[4], bfr[4];
#pragma unroll
      for (int i = 0; i < 4; ++i)
        af[i] = *(const bf16x8*)&sAB[(mbase + i * 16 + lm) * 64 + csw];
#pragma unroll
      for (int j = 0; j < 4; ++j)
        bfr[j] = *(const bf16x8*)&sAB[8192 + (nbase + j * 16 + lm) * 64 + csw];
#pragma unroll
      for (int i = 0; i < 4; ++i)
#pragma unroll
        for (int j = 0; j < 4; ++j)
          acc[i][j] = __builtin_amdgcn_mfma_f32_16x16x32_bf16(af[i], bfr[j], acc[i][j], 0, 0, 0);
    }
    __syncthreads();
  }

  // C/D layout: col = lane&15, row = (lane>>4)*4 + reg  [m89-verified]
  float* dst = sk ? p1 : p0;
#pragma unroll
  for (int i = 0; i < 4; ++i) {
    const int grow0 = rowA0 + mbase + i * 16 + lq * 4;
#pragma unroll
    for (int j = 0; j < 4; ++j) {
      const int gcol = rowB0 + nbase + j * 16 + lm;
#pragma unroll
      for (int r = 0; r < 4; ++r)
        dst[(size_t)(grow0 + r) * D_DIM + gcol] = acc[i][j][r];
    }
  }
}

// ---------------- K1e: reduce partials + quaternion epilogue (NO atomics) ----------------
// R2 lesson: same-address atomicAdds serialize (~31cy each). Grid-stride (G11),
// 2048 blocks; wave shuffle-reduce -> LDS -> one plain store to driftPart[bid].
__global__ __launch_bounds__(256) void k_quat(
    const float* __restrict__ p1, const float* __restrict__ bphi,
    const float* __restrict__ state, float* __restrict__ out,
    unsigned short* __restrict__ nsb, float* __restrict__ driftPart) {
  __shared__ float sW[4];
  const unsigned int nth = gridDim.x * 256u;
  float driftLocal = 0.0f;
  for (unsigned int idx = blockIdx.x * 256u + threadIdx.x; idx < 2097152u; idx += nth) {
    const unsigned int qc = idx & 1023u;
    float4 v0 = ((const float4*)out)[idx];
    float4 v1 = ((const float4*)p1)[idx];
    float4 bq = ((const float4*)bphi)[qc];
    float vx = v0.y + v1.y + bq.y;
    float vy = v0.z + v1.z + bq.z;
    float vz = v0.w + v1.w + bq.w;
    float th = sqrtf(vx * vx + vy * vy + vz * vz) + EPSF;
    float st = sinf(th), ct = cosf(th);
    float sc = st / th;
    float rw = ct, rx = vx * sc, ry = vy * sc, rz = vz * sc;
    float4 sq = ((const float4*)state)[idx];
    float aw = sq.x, ax = sq.y, ay = sq.z, az = sq.w;
    float nw = aw * rw - ax * rx - ay * ry - az * rz;
    float nx = aw * rx + rw * ax + (ay * rz - az * ry);
    float ny = aw * ry + rw * ay + (az * rx - ax * rz);
    float nz = aw * rz + rw * az + (ax * ry - ay * rx);
    float nrm = sqrtf(nw * nw + nx * nx + ny * ny + nz * nz);
    float invn = 1.0f / (nrm + EPSF);
    nw *= invn; nx *= invn; ny *= invn; nz *= invn;
    float n2 = sqrtf(nw * nw + nx * nx + ny * ny + nz * nz);
    driftLocal += fabsf(n2 - 1.0f);
    float4 o; o.x = nw; o.y = nx; o.z = ny; o.w = nz;
    ((float4*)out)[idx] = o;
    ((ushort4*)nsb)[idx] = make_ushort4(f2bf(nw), f2bf(nx), f2bf(ny), f2bf(nz));
  }
#pragma unroll
  for (int off = 32; off > 0; off >>= 1) driftLocal += __shfl_down(driftLocal, off);
  if ((threadIdx.x & 63) == 0) sW[threadIdx.x >> 6] = driftLocal;
  __syncthreads();
  if (threadIdx.x == 0)
    driftPart[blockIdx.x] = sW[0] + sW[1] + sW[2] + sW[3];
}

// ---------------- K2: GEMM2 (logits = ns * W_dde^T), 64x128 tile, split-K=4 ----------------
// CONTROL this round. BM=64 BN=128 BK=64, LDS 24KB, grid (8,32,4) = 1024 blocks.
__global__ __launch_bounds__(256) void k_gemm2(
    const unsigned short* __restrict__ A /* ns bf16 [2048,4096] */,
    const unsigned short* __restrict__ Bm /* W_dde bf16 [1024,4096] */,
    float* __restrict__ part /* ws: [4][2048][1024] f32 partial logits */) {
  __shared__ __align__(16) unsigned short sAB[64 * 64 + 128 * 64];  // 24 KB
  const int t = threadIdx.x;
  const int lane = t & 63;
  const int w = t >> 6;
  const int bn = blockIdx.x;   // 0..7
  const int bm = blockIdx.y;   // 0..31
  const int sk = blockIdx.z;   // 0..3
  const int rowA0 = bm * 64;
  const int rowB0 = bn * 128;
  const int kbeg = sk * 1024;

  const unsigned short* gA[2]; const unsigned short* gB[4];
  unsigned short *lA[2], *lB[4];
#pragma unroll
  for (int p = 0; p < 2; ++p) {
    const int c = t + p * 256;
    const int row = c >> 3;
    const int kcg = (c & 7) ^ (row & 7);
    gA[p] = A + (size_t)(rowA0 + row) * D_DIM + kbeg + kcg * 8;
    lA[p] = &sAB[c * 8];
  }
#pragma unroll
  for (int p = 0; p < 4; ++p) {
    const int c = t + p * 256;
    const int row = c >> 3;
    const int kcg = (c & 7) ^ (row & 7);
    gB[p] = Bm + (size_t)(rowB0 + row) * D_DIM + kbeg + kcg * 8;
    lB[p] = &sAB[4096 + c * 8];
  }

  f32x4 acc[2][4] = {};
  const int lm = lane & 15;
  const int lq = lane >> 4;
  const int mbase = (w >> 1) * 32;
  const int nbase = (w & 1) * 64;
  const int rsw = lm & 7;

  for (int k0 = 0; k0 < 1024; k0 += 64) {
#pragma unroll
    for (int p = 0; p < 2; ++p)
      __builtin_amdgcn_global_load_lds((const GLOBAL_AS unsigned int*)(gA[p] + k0), (LDS_AS unsigned int*)lA[p], 16, 0, 0);
#pragma unroll
    for (int p = 0; p < 4; ++p)
      __builtin_amdgcn_global_load_lds((const GLOBAL_AS unsigned int*)(gB[p] + k0), (LDS_AS unsigned int*)lB[p], 16, 0, 0);
    __syncthreads();
#pragma unroll
    for (int ks = 0; ks < 2; ++ks) {
      const int kc = ks * 4 + lq;
      const int csw = (kc ^ rsw) * 8;
      bf16x8 af[2], bfr[4];
#pragma unroll
      for (int i = 0; i < 2; ++i)
        af[i] = *(const bf16x8*)&sAB[(mbase + i * 16 + lm) * 64 + csw];
#pragma unroll
      for (int j = 0; j < 4; ++j)
        bfr[j] = *(const bf16x8*)&sAB[4096 + (nbase + j * 16 + lm) * 64 + csw];
#pragma unroll
      for (int i = 0; i < 2; ++i)
#pragma unroll
        for (int j = 0; j < 4; ++j)
          acc[i][j] = __builtin_amdgcn_mfma_f32_16x16x32_bf16(af[i], bfr[j], acc[i][j], 0, 0, 0);
    }
    __syncthreads();
  }

  float* pS = part + (size_t)sk * (2048u * 1024u);
#pragma unroll
  for (int i = 0; i < 2; ++i) {
    const int grow0 = rowA0 + mbase + i * 16 + lq * 4;
#pragma unroll
    for (int j = 0; j < 4; ++j) {
      const int gcol = rowB0 + nbase + j * 16 + lm;
#pragma unroll
      for (int r = 0; r < 4; ++r)
        pS[(size_t)(grow0 + r) * Q_DIM + gcol] = acc[i][j][r];
    }
  }
}

// ---------------- K3: reduce partials + gate + blend; block 0 also reduces eta ----------------
// Grid-stride (G11), 2048 blocks.
__global__ __launch_bounds__(256) void k_blend(
    const float* __restrict__ part, const float* __restrict__ bdde,
    const float* __restrict__ state, float* __restrict__ out,
    const float* __restrict__ driftPart, int eta_idx) {
  __shared__ float sW[4];
  const unsigned int nth = gridDim.x * 256u;
  for (unsigned int idx = blockIdx.x * 256u + threadIdx.x; idx < 2097152u; idx += nth) {
    const unsigned int q = idx & 1023u;
    float z = bdde[q];
#pragma unroll
    for (int k = 0; k < 4; ++k) z += part[idx + k * 2097152u];
    float gate = 1.0f / (1.0f + expf(-z));
    float4 sq = ((const float4*)state)[idx];
    float4 nq = ((const float4*)out)[idx];   // ns f32 written by k_quat
    float4 f;
    f.x = sq.x + gate * (nq.x - sq.x);
    f.y = sq.y + gate * (nq.y - sq.y);
    f.z = sq.z + gate * (nq.z - sq.z);
    f.w = sq.w + gate * (nq.w - sq.w);
    ((float4*)out)[idx] = f;                 // in-place: same thread read->write
  }
  if (blockIdx.x == 0) {                     // uniform branch: whole block 0
    float s = 0.0f;
    for (int k = threadIdx.x; k < 2048; k += 256) s += driftPart[k];
#pragma unroll
    for (int off = 32; off > 0; off >>= 1) s += __shfl_down(s, off);
    if ((threadIdx.x & 63) == 0) sW[threadIdx.x >> 6] = s;
    __syncthreads();
    if (threadIdx.x == 0)
      out[eta_idx] = (sW[0] + sW[1] + sW[2] + sW[3]) * (1.0f / 2097152.0f);
  }
}

extern "C" void kernel_launch(void* const* d_in, const int* in_sizes, int n_in,
                              void* d_out, int out_size, void* d_ws, size_t ws_size,
                              hipStream_t stream) {
  const float* x     = (const float*)d_in[0];
  const float* state = (const float*)d_in[1];
  const float* wphi  = (const float*)d_in[2];
  const float* bphi  = (const float*)d_in[3];
  const float* wdde  = (const float*)d_in[4];
  const float* bdde  = (const float*)d_in[5];
  float* out = (float*)d_out;
  char* ws = (char*)d_ws;

  // ws (>=110MB, proven R2/R3):
  //   [0,8K) driftPart (reuses xb head, dead after gemm1s)
  //   [0,16M) xb | [16M,48M) wphib            (dead after gemm1s)
  //   [32K, 32M+32K) part (gemm2 partials; overwrites dead xb/wphib region)
  //   [48M,80M) p1 (dead after quat) | [80M,88M) wddeb | [88M,104M) nsb
  unsigned short* xb    = (unsigned short*)(ws);
  unsigned short* wphib = (unsigned short*)(ws + 16777216);
  float*          p1    = (float*)(ws + 50331648);
  unsigned short* wddeb = (unsigned short*)(ws + 83886080);
  unsigned short* nsb   = (unsigned short*)(ws + 92274688);
  float*          driftPart = (float*)(ws);
  float*          part  = (float*)(ws + 32768);

  k_convert<<<2048, 256, 0, stream>>>(x, wphi, wdde, xb, wphib, wddeb);
  dim3 g1(32, 16, 2);
  k_gemm1s<<<g1, 256, 0, stream>>>(xb, wphib, out, p1);
  k_quat<<<2048, 256, 0, stream>>>(p1, bphi, state, out, nsb, driftPart);
  dim3 g2(8, 32, 4);
  k_gemm2<<<g2, 256, 0, stream>>>(nsb, wddeb, part);
  k_blend<<<2048, 256, 0, stream>>>(part, bdde, state, out, driftPart, out_size - 1);
}